// Round 3
// baseline (126.120 us; speedup 1.0000x reference)
//
#include <hip/hip_runtime.h>

// Radon transform: data (1,1,512,512) f32, angles (256,) f32 -> out (1,1,256,512) f32.
// Block = (angle, 64-col x-chunk), 512 threads (8 waves). y is cut into 11 chunks
// (10x48 + 1x32). For each chunk, the rotated patch's bbox (<=82x81) is staged into
// one of TWO LDS buffers (double-buffered, 63.6 KB total, fits the 64 KB static
// limit) and bilinear-sampled from LDS. Chunk k+1's staging (global_load_lds
// width=16 from a zero-PADDED image in d_ws) is issued BEFORE sampling chunk k, so
// the implicit vmcnt(0) drain at the next __syncthreads lands after a full compute
// phase -> staging latency hidden, ONE barrier per chunk (was 2, with the drain
// right after issue). STRIDE is a compile-time template param (95 or 97 by sign(c),
// block-uniform): per-lane bank step |c +- s| in [1,1.414] (~conflict-free) and the
// 4 bilinear taps compile to two ds_read2_b32 feeding packed v_pk_fma_f32 lerps.
// launch_bounds(512,4): 2 blocks/CU are LDS-bound anyway; give the allocator VGPRs
// to keep ds_reads in flight (round-1's (512,8) pinned the kernel at 16 VGPRs).

#define HH 512
#define WW 512
#define NA 256
#define XC 64
#define NXC (WW / XC)          // 8 x-chunks
#define NW 8                   // waves per block
#define YC 48                  // y-chunk rows (last chunk: 32)
#define NCH 11                 // 10*48 + 32 = 512
#define LASTR 32
#define ROWS_MAX 82            // bbox rows <= 63|s|+47|c|+2 <= 80.6 -> 81 (+1 margin)
#define SMAX 97                // LDS row allocation stride (max of 95/97)
#define PAD 112                // >= 256*sqrt(2)-256+2
#define PW (WW + 2 * PAD)      // 736
#define PH (HH + 2 * PAD)      // 736

typedef float f32x2 __attribute__((ext_vector_type(2)));

__global__ __launch_bounds__(256) void pad_kernel(
    const float* __restrict__ img, float* __restrict__ P)
{
    const int c = blockIdx.x * 256 + threadIdx.x;
    const int r = blockIdx.y;
    if (c >= PW) return;
    const int gr = r - PAD, gc = c - PAD;
    float v = 0.0f;
    if ((unsigned)gr < (unsigned)HH && (unsigned)gc < (unsigned)WW)
        v = img[gr * WW + gc];
    P[r * PW + c] = v;
}

__device__ __forceinline__ float fract_f(float x) {
#if __has_builtin(__builtin_amdgcn_fractf)
    return __builtin_amdgcn_fractf(x);
#else
    return x - floorf(x);
#endif
}

struct BB {
    int c_lo, r_lo, bh, bw;
    bool valid;
    float v0;
};

template <int STRIDE, int NYS>
__device__ __forceinline__ void sample_chunk(
    const float* __restrict__ tb, const BB& b,
    const float s, const float c, const float u, const int wid,
    float& acc0, float& acc1)
{
    const float bc = fmaf(c, u, 255.5f - (float)b.c_lo);
    const float br = fmaf(-s, u, 255.5f - (float)b.r_lo);
    const float vy0 = b.v0 + (float)(wid * NYS);

    f32x2 crx, stepv;
    crx.x = fmaf(s, vy0, bc);     // local col coord, >= 0
    crx.y = fmaf(c, vy0, br);     // local row coord, >= 0
    stepv.x = s;
    stepv.y = c;

#pragma unroll
    for (int i = 0; i < NYS; ++i) {
        const float cxl = crx.x;
        const float rxl = crx.y;
        const int ci = (int)cxl;             // == floor for >= 0
        const int ri = (int)rxl;
        const float wx1 = fract_f(cxl);
        const float wy1 = fract_f(rxl);

        __builtin_assume(ri >= 0 && ri < ROWS_MAX);
        __builtin_assume(ci >= 0 && ci < SMAX);
        const int ad = ri * STRIDE + ci;

        // two ds_read2_b32: (v00,v01) at dword offsets (0,1) and
        // (v10,v11) at (STRIDE,STRIDE+1) — immediates encodable
        f32x2 top, bot;
        top.x = tb[ad];
        top.y = tb[ad + 1];
        bot.x = tb[ad + STRIDE];
        bot.y = tb[ad + STRIDE + 1];

        f32x2 wyv;
        wyv.x = wy1;
        wyv.y = wy1;
        const f32x2 pv = __builtin_elementwise_fma(wyv, bot - top, top);

        acc0 += pv.x;
        acc1 = fmaf(wx1, pv.y - pv.x, acc1);

        crx += stepv;
    }
}

template <bool PADDED, int STRIDE>
__device__ __forceinline__ void radon_body(
    const float* __restrict__ src, float* __restrict__ tile,
    const float s, const float c, const int lane, const int wid, const int x0,
    float& acc0, float& acc1)
{
    constexpr bool CPOS = (STRIDE == 95);   // stride picked by sign(c)

    const float u  = (float)(x0 + lane) + (0.5f - 256.0f);
    const float u0 = (float)x0 + (0.5f - 256.0f);
    const float u1 = u0 + (float)(XC - 1);

    // origin-shifted padded base: valid for row/col indices in [-PAD, WW+PAD)
    const float* __restrict__ Porg = PADDED ? (src + PAD * PW + PAD) : src;

    // sign(c) is known at compile time (s >= 0 always): each bbox bound is a
    // single affine expression — no fmin/fmax trees.
    auto bbox = [&](int k) -> BB {
        BB b;
        const int rows = (k == NCH - 1) ? LASTR : YC;
        b.v0 = (float)(k * YC) - 255.5f;
        const float v1 = b.v0 + (float)(rows - 1);
        float cx_min, cx_max, rx_min, rx_max;
        if (CPOS) {
            cx_min = fmaf(c, u0, fmaf(s, b.v0, 255.5f));
            cx_max = fmaf(c, u1, fmaf(s, v1,   255.5f));
            rx_min = fmaf(-s, u1, fmaf(c, b.v0, 255.5f));
            rx_max = fmaf(-s, u0, fmaf(c, v1,   255.5f));
        } else {
            cx_min = fmaf(c, u1, fmaf(s, b.v0, 255.5f));
            cx_max = fmaf(c, u0, fmaf(s, v1,   255.5f));
            rx_min = fmaf(-s, u1, fmaf(c, v1,   255.5f));
            rx_max = fmaf(-s, u0, fmaf(c, b.v0, 255.5f));
        }
        b.c_lo = (int)floorf(cx_min);
        b.r_lo = (int)floorf(rx_min);
        const int c_hi = (int)floorf(cx_max) + 1;
        const int r_hi = (int)floorf(rx_max) + 1;
        b.bh = min(r_hi - b.r_lo + 1, ROWS_MAX);
        b.bw = min(c_hi - b.c_lo + 1, SMAX);
        b.valid = (b.c_lo <= WW - 1) & (c_hi >= 0) & (b.r_lo <= HH - 1) & (r_hi >= 0);
        return b;
    };

    auto stage = [&](int buf, const BB& b) {
        float* __restrict__ base = tile + buf * (ROWS_MAX * SMAX);
        if (PADDED) {
            // one global_load_lds_dwordx4 per bbox row: lanes 0..20 each move
            // 16 B -> LDS row base + lane*16 (336 B covers bw <= 82 dwords;
            // 336 <= STRIDE*4 so no spill into the next LDS row). All taps of
            // any chunk stay inside the padded image (|coord| <= 361.4 + 255.5
            // -> indices in [-106, 617] subset of [-112, 624)).
            if (lane < 21) {
                const float* g = Porg + (b.r_lo + wid) * PW + b.c_lo + lane * 4;
                float* l = base + wid * STRIDE;
                for (int r = wid; r < b.bh; r += NW) {
                    __builtin_amdgcn_global_load_lds(
                        (__attribute__((address_space(1))) const void*)g,
                        (__attribute__((address_space(3))) void*)l, 16, 0, 0);
                    g += NW * PW;
                    l += NW * STRIDE;
                }
            }
        } else {
            for (int r = wid; r < b.bh; r += NW) {
                const int gr = b.r_lo + r;
                const bool row_ok = ((unsigned)gr < (unsigned)HH);
                const float* __restrict__ rowp = src + gr * WW;
                for (int cc = lane; cc < b.bw; cc += 64) {
                    const int gc = b.c_lo + cc;
                    float v = 0.0f;
                    if (row_ok) {
                        const int gcl = min(max(gc, 0), WW - 1);
                        const float t = rowp[gcl];
                        v = ((unsigned)gc < (unsigned)WW) ? t : 0.0f;
                    }
                    base[r * STRIDE + cc] = v;
                }
            }
        }
    };

    // ---- software pipeline: stage(k+1) issued before sample(k) ----
    BB cur = bbox(0);
    if (cur.valid) stage(0, cur);

#pragma unroll 1
    for (int k = 0; k < NCH; ++k) {
        BB nxt;
        nxt.valid = false;
        if (k + 1 < NCH) nxt = bbox(k + 1);

        // waits each wave's own global_load_lds (vmcnt(0)) — for k>=1 those
        // were issued a full compute phase ago -> latency hidden. Also orders
        // last iteration's sampling before this iteration's overwrite.
        __syncthreads();

        if (nxt.valid) stage((k + 1) & 1, nxt);

        if (cur.valid) {
            const float* tb = tile + (k & 1) * (ROWS_MAX * SMAX);
            if (k == NCH - 1)
                sample_chunk<STRIDE, LASTR / NW>(tb, cur, s, c, u, wid, acc0, acc1);
            else
                sample_chunk<STRIDE, YC / NW>(tb, cur, s, c, u, wid, acc0, acc1);
        }
        cur = nxt;
    }
}

template <bool PADDED>
__global__ __launch_bounds__(512, 4) void radon_kernel(
    const float* __restrict__ src,   // PADDED ? padded image : raw image
    const float* __restrict__ angles, float* __restrict__ out)
{
    __shared__ float tile[2 * ROWS_MAX * SMAX];   // 63,632 B -> 2 blocks/CU

    const int tid  = threadIdx.x;
    const int lane = tid & 63;
    const int wid  = tid >> 6;     // 0..7

    const int a  = blockIdx.x >> 3;
    const int x0 = (blockIdx.x & 7) * XC;

    float s, c;
    sincosf(angles[a], &s, &c);

    // bank = (ri*stride + ci) % 32; stride 95 (== -1 mod 32) -> bank step c+s,
    // stride 97 (== +1) -> bank step c-s. s>=0: pick so |step| >= 1 always.
    // Block-uniform branch (same c for the whole block) -> __syncthreads safe.
    float acc0 = 0.0f, acc1 = 0.0f;
    if (c >= 0.0f)
        radon_body<PADDED, 95>(src, tile, s, c, lane, wid, x0, acc0, acc1);
    else
        radon_body<PADDED, 97>(src, tile, s, c, lane, wid, x0, acc0, acc1);

    // reduce the 8 y-groups per column and store (each block owns its outputs)
    __syncthreads();
    tile[tid] = acc0 + acc1;
    __syncthreads();
    if (tid < 64) {
        float r = tile[tid];
#pragma unroll
        for (int k = 1; k < NW; ++k) r += tile[k * 64 + tid];
        out[a * WW + x0 + tid] = r;
    }
}

extern "C" void kernel_launch(void* const* d_in, const int* in_sizes, int n_in,
                              void* d_out, int out_size, void* d_ws, size_t ws_size,
                              hipStream_t stream) {
    const float* img    = (const float*)d_in[0];
    const float* angles = (const float*)d_in[1];
    float* out = (float*)d_out;
    float* P   = (float*)d_ws;

    const bool padded = (ws_size >= (size_t)PW * PH * sizeof(float));

    if (padded) {
        pad_kernel<<<dim3((PW + 255) / 256, PH), 256, 0, stream>>>(img, P);
        radon_kernel<true><<<dim3(NA * NXC), 512, 0, stream>>>(P, angles, out);
    } else {
        radon_kernel<false><<<dim3(NA * NXC), 512, 0, stream>>>(img, angles, out);
    }
}